// Round 16
// baseline (1796.589 us; speedup 1.0000x reference)
//
#include <hip/hip_runtime.h>

#define N_NODES 50000
#define E_EDGES 800000
#define NG 16
#define DD 64
#define HH 128
#define NB_SCAN 49
#define EREP 32

typedef __attribute__((ext_vector_type(8))) __bf16 bf16x8;
typedef __attribute__((ext_vector_type(4))) float f32x4;
typedef unsigned int uint;
typedef unsigned short ushort;
typedef __attribute__((ext_vector_type(4))) uint uint4v;

#define MFMA16(a,b,c) __builtin_amdgcn_mfma_f32_16x16x32_bf16((a),(b),(c),0,0,0)

__device__ __forceinline__ ushort f2bf(float f){
  uint u = __builtin_bit_cast(uint, f);
  u += 0x7fffu + ((u >> 16) & 1u);
  return (ushort)(u >> 16);
}
__device__ __forceinline__ uint pk2(float a, float b){
  return (uint)f2bf(a) | ((uint)f2bf(b) << 16);
}
__device__ __forceinline__ float bflo(uint u){ return __builtin_bit_cast(float, u << 16); }
__device__ __forceinline__ float bfhi(uint u){ return __builtin_bit_cast(float, u & 0xffff0000u); }

// LDS-visibility barrier (no vmcnt drain)
__device__ __forceinline__ void bar(){
  asm volatile("s_waitcnt lgkmcnt(0)" ::: "memory");
  __builtin_amdgcn_s_barrier();
}
#define VMWAIT(n) asm volatile("s_waitcnt vmcnt(" #n ")" ::: "memory")

// async global->LDS, 16B per lane
__device__ __forceinline__ void gload16(const void* g, void* l){
  __builtin_amdgcn_global_load_lds(
      (const __attribute__((address_space(1))) unsigned int*)g,
      (__attribute__((address_space(3))) unsigned int*)l, 16, 0, 0);
}

// ---- pitch-256B LDS helpers (swizzled 16B chunks) ----
__device__ __forceinline__ bf16x8 ldfrag(const char* base, int row, int byteoff){
  uint4v v = *(const uint4v*)(base + row*256 + (byteoff ^ ((row & 7) << 4)));
  return __builtin_bit_cast(bf16x8, v);
}
__device__ __forceinline__ uint4v ld_chunk(const char* base, int row, int c16){
  return *(const uint4v*)(base + row*256 + ((c16*16) ^ ((row & 7) << 4)));
}
__device__ __forceinline__ void st_h(char* base, int row, int col, float v){
  *(ushort*)(base + row*256 + ((col*2) ^ ((row & 7) << 4))) = f2bf(v);
}
__device__ __forceinline__ void st_chunk(char* base, int row, int c16, uint4v v){
  *(uint4v*)(base + row*256 + ((c16*16) ^ ((row & 7) << 4))) = v;
}
// ---- pitch-128B LDS helpers ----
__device__ __forceinline__ bf16x8 ldfrag128(const char* base, int row, int byteoff){
  uint4v v = *(const uint4v*)(base + row*128 + (byteoff ^ ((row & 7) << 4)));
  return __builtin_bit_cast(bf16x8, v);
}
__device__ __forceinline__ uint4v ld_chunk128(const char* base, int row, int c16){
  return *(const uint4v*)(base + row*128 + ((c16*16) ^ ((row & 7) << 4)));
}
__device__ __forceinline__ void st_chunk128(char* base, int row, int c16, uint4v v){
  *(uint4v*)(base + row*128 + ((c16*16) ^ ((row & 7) << 4))) = v;
}
__device__ __forceinline__ void st_h128(char* base, int row, int col, float v){
  *(ushort*)(base + row*128 + ((col*2) ^ ((row & 7) << 4))) = f2bf(v);
}
__device__ __forceinline__ void pack16_128(char* dst, int r, int c16, const float* src){
  float4 lo = *(const float4*)src;
  float4 hi = *(const float4*)(src + 4);
  uint4v v; v.x = pk2(lo.x, lo.y); v.y = pk2(lo.z, lo.w);
  v.z = pk2(hi.x, hi.y); v.w = pk2(hi.z, hi.w);
  st_chunk128(dst, r, c16, v);
}

// node-kernel helpers (4 waves) — R2-proven
__device__ __forceinline__ void stage_b(char* sB, const ushort* wt,
                                        int Nout, int Ktot, int koff, int t, int stride){
  for (int task = t; task < Nout*16; task += stride){
    int n = task >> 4, c = task & 15;
    uint4v v = *(const uint4v*)(wt + (long)n*Ktot + koff + c*8);
    st_chunk(sB, n, c, v);
  }
}
template<int NT>
__device__ __forceinline__ void gemm_acc(const char* A, const char* B,
                                         int wv, int l15, int lhi, f32x4* acc){
  #pragma unroll
  for (int kt = 0; kt < 4; ++kt){
    bf16x8 a = ldfrag(A, wv*16 + l15, kt*64 + lhi*16);
    #pragma unroll
    for (int n = 0; n < NT; ++n){
      bf16x8 bb = ldfrag(B, n*16 + l15, kt*64 + lhi*16);
      acc[n] = MFMA16(a, bb, acc[n]);
    }
  }
}
template<int NT, bool RELU>
__device__ __forceinline__ void epi_lds(char* dst, const f32x4* acc, const float* bias,
                                        int wv, int l15, int lhi){
  #pragma unroll
  for (int n = 0; n < NT; ++n){
    float bv = bias[n*16 + l15];
    #pragma unroll
    for (int j = 0; j < 4; ++j){
      int r = wv*16 + lhi*4 + j;
      float v = acc[n][j] + bv;
      if (RELU) v = fmaxf(v, 0.f);
      st_h(dst, r, n*16 + l15, v);
    }
  }
}

// ---------------- x fp32 -> bf16 ----------------
__global__ void convert_x(const float* __restrict__ x, ushort* __restrict__ xbf){
  int i = blockIdx.x*256 + threadIdx.x;
  if (i < (N_NODES*DD)/8){
    float4 lo = *(const float4*)(x + (long)i*8);
    float4 hi = *(const float4*)(x + (long)i*8 + 4);
    uint4v v; v.x = pk2(lo.x, lo.y); v.y = pk2(lo.z, lo.w);
    v.z = pk2(hi.x, hi.y); v.w = pk2(hi.z, hi.w);
    *(uint4v*)(xbf + (long)i*8) = v;
  }
}

// ---------------- weight pack: fp32 [L][K][N] -> bf16 transposed [N][K] ----------
__global__ void pack_weights(const float* __restrict__ e1, const float* __restrict__ e2,
                             const float* __restrict__ e3, const float* __restrict__ n12,
                             const float* __restrict__ n21, const float* __restrict__ n22,
                             ushort* __restrict__ out){
  int idx = blockIdx.x * 256 + threadIdx.x;   // 2*114688
  int l = idx / 114688, r = idx % 114688;
  const float* src; int K, N, off;
  if      (r <  32768){ src = e1;  K = 256; N = 128; off = 0; }
  else if (r <  49152){ src = e2;  K = 128; N = 128; off = 32768; }
  else if (r <  57344){ src = e3;  K = 128; N = 64;  off = 49152; }
  else if (r <  73728){ src = n12; K = 128; N = 128; off = 57344; }
  else if (r < 106496){ src = n21; K = 256; N = 128; off = 73728; }
  else                { src = n22; K = 128; N = 64;  off = 106496; }
  int q = r - off; int k = q / N; int n = q % N;
  out[(long)l*139264 + off + n*K + k] = f2bf(src[(long)l*K*N + q]);
}

// fused weight Wc[n][k], k<64: n1_w1[k][n]; k>=64: sum_m e_w3[k-64][m]*n1_w1[64+m][n]
__global__ void make_wc(const float* __restrict__ n1w1, const float* __restrict__ ew3,
                        const float* __restrict__ n1b1, const float* __restrict__ eb3,
                        ushort* __restrict__ packed, float* __restrict__ biasc){
  int l = blockIdx.x, t = threadIdx.x;
  const float* W1 = n1w1 + (long)l*128*128;
  const float* W3 = ew3 + (long)l*128*64;
  ushort* wc = packed + (long)l*139264 + 114688;
  for (int i = t; i < 8192; i += 256){
    int k = i >> 7, n = i & 127;
    wc[n*192 + k] = f2bf(W1[k*128 + n]);
  }
  for (int i = t; i < 16384; i += 256){
    int k2 = i >> 7, n = i & 127;
    float s = 0.f;
    for (int m = 0; m < 64; ++m) s += W3[k2*64 + m] * W1[(64 + m)*128 + n];
    wc[n*192 + 64 + k2] = f2bf(s);
  }
  if (t < 128){
    float s = n1b1[l*128 + t];
    for (int m = 0; m < 64; ++m) s += eb3[l*64 + m] * W1[(64 + m)*128 + t];
    biasc[l*128 + t] = s;
  }
}

// ---------------- counts / CSR ----------------
__global__ void hist_kernel(const int* __restrict__ edge_index, const int* __restrict__ batch,
                            int* __restrict__ deg, float* __restrict__ cnt_eb){
  __shared__ float h[NG];
  int t = threadIdx.x;
  if (t < NG) h[t] = 0.f;
  __syncthreads();
  int e = blockIdx.x * 256 + t;
  if (e < E_EDGES){
    atomicAdd(deg + edge_index[E_EDGES + e], 1);
    atomicAdd(&h[batch[edge_index[e]]], 1.f);
  }
  __syncthreads();
  if (t < NG) atomicAdd(cnt_eb + t, h[t]);
}
__global__ void count_nodes_kernel(const int* __restrict__ batch, float* __restrict__ cnt_b){
  __shared__ float h[NG];
  int t = threadIdx.x;
  if (t < NG) h[t] = 0.f;
  __syncthreads();
  int n = blockIdx.x * 256 + t;
  if (n < N_NODES) atomicAdd(&h[batch[n]], 1.f);
  __syncthreads();
  if (t < NG) atomicAdd(cnt_b + t, h[t]);
}
__global__ void scan_a(const int* __restrict__ deg, int* __restrict__ bsum){
  __shared__ int red[1024];
  int i = blockIdx.x*1024 + threadIdx.x;
  red[threadIdx.x] = (i < N_NODES) ? deg[i] : 0;
  __syncthreads();
  for (int s = 512; s > 0; s >>= 1){
    if ((int)threadIdx.x < s) red[threadIdx.x] += red[threadIdx.x + s];
    __syncthreads();
  }
  if (threadIdx.x == 0) bsum[blockIdx.x] = red[0];
}
__global__ void scan_b(const int* __restrict__ bsum, int* __restrict__ bbase){
  if (threadIdx.x == 0){
    int run = 0;
    for (int b = 0; b < NB_SCAN; ++b){ int v = bsum[b]; bbase[b] = run; run += v; }
  }
}
__global__ void scan_c(const int* __restrict__ deg, const int* __restrict__ bbase,
                       int* __restrict__ off, int* __restrict__ cursor){
  __shared__ int sc[1024];
  int i = blockIdx.x*1024 + threadIdx.x;
  int v = (i < N_NODES) ? deg[i] : 0;
  sc[threadIdx.x] = v;
  __syncthreads();
  for (int d = 1; d < 1024; d <<= 1){
    int add = ((int)threadIdx.x >= d) ? sc[threadIdx.x - d] : 0;
    __syncthreads();
    sc[threadIdx.x] += add;
    __syncthreads();
  }
  if (i < N_NODES){
    int ex = sc[threadIdx.x] - v + bbase[blockIdx.x];
    off[i] = ex; cursor[i] = ex;
  }
}
__global__ void fill_kernel(const int* __restrict__ edge_index, int* __restrict__ cursor,
                            int* __restrict__ pos){
  int e = blockIdx.x*256 + threadIdx.x;
  if (e < E_EDGES){
    int c = edge_index[E_EDGES + e];
    pos[e] = atomicAdd(&cursor[c], 1);
  }
}

// ============ edge_fused v16: async W staging (gload_lds ring), gathers in prologue ====
// LDS: X@0(8K) A0@8192(8K) A1@16384(8K) W0@24576(16K) W1@40960(16K) OV@57344(16K)
template<bool CSR, bool EBF>
__global__ __launch_bounds__(256, 2) void edge_fused(
    const ushort* __restrict__ xbf, const float* e_f32, const ushort* e_bf,
    const float* __restrict__ u_cur,
    const int* __restrict__ ei, const int* __restrict__ batch,
    const int* __restrict__ pos_arr,
    const ushort* __restrict__ w1t, const ushort* __restrict__ w2t,
    const ushort* __restrict__ w3t, const ushort* __restrict__ wct,
    const ushort* __restrict__ w5t,
    const float* __restrict__ be1, const float* __restrict__ be2,
    const float* __restrict__ be3, const float* __restrict__ biasc,
    const float* __restrict__ bn12,
    float* e_outf, const float* __restrict__ e_resid,
    ushort* __restrict__ se_buf, float* __restrict__ agg_sum,
    float* __restrict__ e_agg_rep, int has_resid)
{
  __shared__ __align__(16) char lds[73728];
  __shared__ float sEagg[NG*DD];
  __shared__ int sRow[64];   // r | eb<<16
  __shared__ int sCol[64];
  __shared__ int sDst[64];   // pos (CSR) or col
  char* X  = lds;
  char* A0 = lds + 8192;
  char* A1 = lds + 16384;
  char* W0 = lds + 24576;
  char* W1 = lds + 40960;
  char* OV = lds + 57344;
  const int t = threadIdx.x;
  const int wv = t >> 6, lane = t & 63, l15 = t & 15, lhi = (t >> 4) & 3;
  const int ebase = blockIdx.x * 64;

  // async W-tile stage (128x64 bf16 = 16KB): source pre-swizzled, dest linear
  auto GL = [&](const ushort* base, long stride, int koff, char* slot){
    #pragma unroll
    for (int it = 0; it < 4; ++it){
      int q = (wv*4 + it)*64 + lane;
      int r = q >> 3, cp = q & 7;
      gload16(base + (long)r*stride + koff + ((cp ^ (r & 7))*8),
              slot + (wv*4 + it)*1024);
    }
  };

  // ---- prologue A: indices, async W(phase1,2), b3 frags ----
  if (t < 64){
    int r = ei[ebase + t];
    int c = ei[E_EDGES + ebase + t];
    sRow[t] = r | (batch[r] << 16);
    sCol[t] = c;
    sDst[t] = CSR ? pos_arr[ebase + t] : c;
  }
  GL(w1t, 256, 0, W0);    // w1 c0
  GL(w1t, 256, 64, W1);   // w1 c1
  bf16x8 b3[4][4];
  #pragma unroll
  for (int n = 0; n < 4; ++n)
    #pragma unroll
    for (int kk = 0; kk < 4; ++kk)
      b3[n][kk] = *(const bf16x8*)(w3t + (long)(n*16 + l15)*128 + kk*32 + lhi*8);
  for (int i = t; i < NG*DD; i += 256) sEagg[i] = 0.f;
  __syncthreads();                    // drain all; idx visible; W0/W1 resident

  // ---- prologue B: ALL gathers to regs; X tile to LDS ----
  uint4v xr[2], xc[2], eu[2];
  float4 ef[4], uu[4];
  #pragma unroll
  for (int it = 0; it < 2; ++it){
    int task = t + it*256, r = task >> 3, c16 = task & 7;
    xr[it] = *(const uint4v*)(xbf + (long)(sRow[r] & 0xffff)*DD + c16*8);
    xc[it] = *(const uint4v*)(xbf + (long)sCol[r]*DD + c16*8);
    if (EBF) eu[it] = *(const uint4v*)(e_bf + (long)(ebase + r)*HH + c16*8);
    else { ef[2*it]   = *(const float4*)(e_f32 + (long)(ebase + r)*DD + c16*8);
           ef[2*it+1] = *(const float4*)(e_f32 + (long)(ebase + r)*DD + c16*8 + 4); }
    uu[2*it]   = *(const float4*)(u_cur + (long)(sRow[r] >> 16)*DD + c16*8);
    uu[2*it+1] = *(const float4*)(u_cur + (long)(sRow[r] >> 16)*DD + c16*8 + 4);
  }
  #pragma unroll
  for (int it = 0; it < 2; ++it){
    int task = t + it*256, r = task >> 3, c16 = task & 7;
    st_chunk128(X, r, c16, xr[it]);
  }
  __syncthreads();                    // all reg gathers retired; X visible; vm=0

  f32x4 acc1[8];
  #pragma unroll
  for (int n = 0; n < 8; ++n) acc1[n] = f32x4{0,0,0,0};
  auto MM128 = [&](const char* A, const char* W, f32x4* acc){
    #pragma unroll
    for (int kt = 0; kt < 2; ++kt){
      bf16x8 a = ldfrag128(A, wv*16 + l15, kt*64 + lhi*16);
      #pragma unroll
      for (int n = 0; n < 8; ++n){
        bf16x8 bb = ldfrag128(W, n*16 + l15, kt*64 + lhi*16);
        acc[n] = MFMA16(a, bb, acc[n]);
      }
    }
  };
  f32x4 acc3[4];
  #pragma unroll
  for (int n = 0; n < 4; ++n) acc3[n] = f32x4{0,0,0,0};
  auto MMOV = [&](int cbase, const char* W, f32x4* acc){
    #pragma unroll
    for (int kt = 0; kt < 2; ++kt){
      bf16x8 a = ldfrag(OV, wv*16 + l15, cbase + kt*64 + lhi*16);
      #pragma unroll
      for (int n = 0; n < 8; ++n){
        bf16x8 bb = ldfrag128(W, n*16 + l15, kt*64 + lhi*16);
        acc[n] = MFMA16(a, bb, acc[n]);
      }
    }
  };
  auto MMOV3 = [&](int cbase, const char* W, f32x4* acc, int kkb){
    #pragma unroll
    for (int kt = 0; kt < 2; ++kt){
      bf16x8 a = ldfrag(OV, wv*16 + l15, cbase + kt*64 + lhi*16);
      #pragma unroll
      for (int n = 0; n < 8; ++n){
        bf16x8 bb = ldfrag128(W, n*16 + l15, kt*64 + lhi*16);
        acc[n] = MFMA16(a, bb, acc[n]);
      }
      #pragma unroll
      for (int n = 0; n < 4; ++n)
        acc3[n] = MFMA16(a, b3[n][kkb + kt], acc3[n]);
    }
  };
  auto EPI = [&](const float* bias, const f32x4* acc, bool relu){
    #pragma unroll
    for (int n = 0; n < 8; ++n){
      int col = n*16 + l15;
      float bv = bias[col];
      #pragma unroll
      for (int j = 0; j < 4; ++j){
        float v = acc[n][j] + bv;
        if (relu) v = fmaxf(v, 0.f);
        st_h(OV, wv*16 + lhi*4 + j, col, v);
      }
    }
  };

  // P1: GEMM1 c0 (X ⊗ W0=w1c0); stage A0<-xc; then GL w1c2->W0
  MM128(X, W0, acc1);
  #pragma unroll
  for (int it = 0; it < 2; ++it){
    int task = t + it*256, r = task >> 3, c16 = task & 7;
    st_chunk128(A0, r, c16, xc[it]);
  }
  bar();
  GL(w1t, 256, 128, W0);              // out=4
  // P2: GEMM1 c1 (A0 ⊗ W1=w1c1); stage A1<-e; then GL w1c3->W1
  MM128(A0, W1, acc1);
  #pragma unroll
  for (int it = 0; it < 2; ++it){
    int task = t + it*256, r = task >> 3, c16 = task & 7;
    if (EBF) st_chunk128(A1, r, c16, eu[it]);
    else {
      uint4v v; v.x = pk2(ef[2*it].x, ef[2*it].y);     v.y = pk2(ef[2*it].z, ef[2*it].w);
      v.z = pk2(ef[2*it+1].x, ef[2*it+1].y); v.w = pk2(ef[2*it+1].z, ef[2*it+1].w);
      st_chunk128(A1, r, c16, v);
    }
  }
  bar();
  GL(w1t, 256, 192, W1);              // out=8
  // P3: GEMM1 c2 (A1 ⊗ W0=w1c2); stage A0<-u(regs); GL w2c0->W0
  VMWAIT(4); __builtin_amdgcn_s_barrier();
  MM128(A1, W0, acc1);
  #pragma unroll
  for (int it = 0; it < 2; ++it){
    int task = t + it*256, r = task >> 3, c16 = task & 7;
    uint4v v; v.x = pk2(uu[2*it].x, uu[2*it].y);     v.y = pk2(uu[2*it].z, uu[2*it].w);
    v.z = pk2(uu[2*it+1].x, uu[2*it+1].y); v.w = pk2(uu[2*it+1].z, uu[2*it+1].w);
    st_chunk128(A0, r, c16, v);
  }
  bar();
  GL(w2t, 128, 0, W0);                // out=8
  // P4: GEMM1 c3 (A0 ⊗ W1=w1c3); epi H1->OV; GL w2c1->W1
  VMWAIT(4); __builtin_amdgcn_s_barrier();
  MM128(A0, W1, acc1);
  EPI(be1, acc1, true);
  bar();
  GL(w2t, 128, 64, W1);               // out=8
  // P5: GEMM2 c0 (OV ⊗ W0=w2c0); GL wc_c0->W0
  VMWAIT(4); __builtin_amdgcn_s_barrier();
  f32x4 acc2[8];
  #pragma unroll
  for (int n = 0; n < 8; ++n) acc2[n] = f32x4{0,0,0,0};
  MMOV(0, W0, acc2);
  bar();
  GL(wct, 192, 0, W0);                // out=8
  // P6: GEMM2 c1 (OV ⊗ W1=w2c1); epi H2->OV; GL wc_c1->W1
  VMWAIT(4); __builtin_amdgcn_s_barrier();
  MMOV(128, W1, acc2);
  EPI(be2, acc2, true);
  bar();
  GL(wct, 192, 64, W1);               // out=8
  // P7: Wc c0 (X ⊗ W0); GL wc_c2->W0
  VMWAIT(4); __builtin_amdgcn_s_barrier();
  f32x4 acc4[8];
  #pragma unroll
  for (int n = 0; n < 8; ++n) acc4[n] = f32x4{0,0,0,0};
  MM128(X, W0, acc4);
  bar();
  GL(wct, 192, 128, W0);              // out=8
  // P8: Wc c1 (OV H2 c0-63 ⊗ W1) + G3(kk0,1); GL w5c0->W1
  VMWAIT(4); __builtin_amdgcn_s_barrier();
  MMOV3(0, W1, acc4, 0);
  bar();
  GL(w5t, 128, 0, W1);                // out=8
  // P9: Wc c2 (OV H2 c64-127 ⊗ W0) + G3(kk2,3); epi H3->OV; GL w5c1->W0
  VMWAIT(4); __builtin_amdgcn_s_barrier();
  MMOV3(128, W0, acc4, 2);
  EPI(biasc, acc4, true);
  bar();
  GL(w5t, 128, 64, W0);               // out=8
  // P10: GEMM5 c0 (OV H3 ⊗ W1=w5c0)
  VMWAIT(4); __builtin_amdgcn_s_barrier();
  f32x4 acc5[8];
  #pragma unroll
  for (int n = 0; n < 8; ++n) acc5[n] = f32x4{0,0,0,0};
  MMOV(0, W1, acc5);
  bar();                              // out=4
  // P11: GEMM5 c1 (OV H3 ⊗ W0=w5c1)
  VMWAIT(0); __builtin_amdgcn_s_barrier();
  MMOV(128, W0, acc5);
  bar();

  // ---- tail ----
  if (CSR){
    #pragma unroll
    for (int n = 0; n < 8; ++n){
      int col = n*16 + l15;
      float bv = bn12[col];
      #pragma unroll
      for (int j = 0; j < 4; ++j)
        st_h(OV, wv*16 + lhi*4 + j, col, acc5[n][j] + bv);
    }
    if (!has_resid){
      #pragma unroll
      for (int n = 0; n < 4; ++n){
        int col = n*16 + l15;
        float bv = be3[col];
        #pragma unroll
        for (int j = 0; j < 4; ++j){
          int row = wv*16 + lhi*4 + j;
          float v = acc3[n][j] + bv;
          st_h128(A0, row, col, v);
          atomicAdd(&sEagg[(sRow[row] >> 16)*DD + col], v);
        }
      }
    } else {
      #pragma unroll
      for (int n = 0; n < 4; ++n){
        int col = n*16 + l15;
        float bv = be3[col];
        #pragma unroll
        for (int j = 0; j < 4; ++j){
          int row = wv*16 + lhi*4 + j;
          float v = acc3[n][j] + bv;
          long eg = (long)(ebase + row)*DD + col;
          e_outf[eg] = v + e_resid[eg];
          atomicAdd(&sEagg[(sRow[row] >> 16)*DD + col], v);
        }
      }
    }
    bar();
    #pragma unroll
    for (int it = 0; it < 4; ++it){
      int task = t + it*256, r = task >> 4, c16 = task & 15;
      *(uint4v*)(se_buf + (long)sDst[r]*HH + c16*8) = ld_chunk(OV, r, c16);
    }
    if (!has_resid){
      ushort* ebf_out = (ushort*)e_outf;
      #pragma unroll
      for (int it = 0; it < 2; ++it){
        int task = t + it*256, r = task >> 3, c16 = task & 7;
        *(uint4v*)(ebf_out + (long)(ebase + r)*HH + c16*8) = ld_chunk128(A0, r, c16);
      }
    }
  } else {
    #pragma unroll
    for (int n = 0; n < 8; ++n){
      int col = n*16 + l15;
      float bv = bn12[col];
      #pragma unroll
      for (int j = 0; j < 4; ++j){
        int row = wv*16 + lhi*4 + j;
        atomicAdd(agg_sum + (long)sDst[row]*HH + col, acc5[n][j] + bv);
      }
    }
    #pragma unroll
    for (int n = 0; n < 4; ++n){
      int col = n*16 + l15;
      float bv = be3[col];
      #pragma unroll
      for (int j = 0; j < 4; ++j){
        int row = wv*16 + lhi*4 + j;
        float v = acc3[n][j] + bv;
        long eg = (long)(ebase + row)*DD + col;
        e_outf[eg] = has_resid ? (v + e_resid[eg]) : v;
        atomicAdd(&sEagg[(sRow[row] >> 16)*DD + col], v);
      }
    }
  }
  __syncthreads();
  float* dst = e_agg_rep + (long)(blockIdx.x & (EREP - 1))*NG*DD;
  for (int i = t; i < NG*DD; i += 256) atomicAdd(dst + i, sEagg[i]);
}

// ---------------- node kernel: mean-gather + node-MLP2; layer0 also emits xbf ---------
template<bool CSR>
__global__ __launch_bounds__(256, 2) void node_kernel(
    const float* __restrict__ x_cur, const float* __restrict__ u_cur,
    const float* __restrict__ x_resid, const int* __restrict__ batch,
    const ushort* __restrict__ se_buf, const int* __restrict__ deg,
    const int* __restrict__ off, const float* __restrict__ agg_sum,
    const ushort* __restrict__ w_n21, const ushort* __restrict__ w_n22,
    const float* __restrict__ b_n21, const float* __restrict__ b_n22,
    float* __restrict__ x_out, ushort* __restrict__ xbf_out,
    float* __restrict__ n_agg, int has_resid)
{
  __shared__ __align__(16) char sA[16384];
  __shared__ __align__(16) char sB[32768];
  __shared__ __align__(16) char sH[16384];
  __shared__ int sBat[64], sDeg[64], sOff[64];
  __shared__ float sRinv[64];
  __shared__ float sNagg[NG*DD];

  const int t = threadIdx.x;
  const int wv = t >> 6, ln = t & 63, l15 = ln & 15, lhi = ln >> 4;
  const int n0 = blockIdx.x * 64;

  if (t < 64){
    int nd = n0 + t;
    int ok = nd < N_NODES;
    sBat[t] = ok ? batch[nd] : 0;
    int d = ok ? deg[nd] : 0;
    sDeg[t] = d;
    sOff[t] = ok ? off[nd] : 0;
    sRinv[t] = 1.f / fmaxf((float)d, 1.f);
  }
  for (int i = t; i < NG*DD; i += 256) sNagg[i] = 0.f;
  __syncthreads();

  float s[32];
  const int r4 = t >> 2, q = t & 3;
  if (CSR){
    #pragma unroll
    for (int k = 0; k < 32; ++k) s[k] = 0.f;
    int d = sDeg[r4], o = sOff[r4];
    for (int i = 0; i < d; ++i){
      const ushort* src = se_buf + (long)(o + i)*HH + q*32;
      #pragma unroll
      for (int c = 0; c < 4; ++c){
        uint4v v = *(const uint4v*)(src + c*8);
        #pragma unroll
        for (int jj = 0; jj < 4; ++jj){
          s[c*8 + jj*2]     += bflo(v[jj]);
          s[c*8 + jj*2 + 1] += bfhi(v[jj]);
        }
      }
    }
    float riv = sRinv[r4];
    #pragma unroll
    for (int k = 0; k < 32; ++k) s[k] *= riv;
  }

  f32x4 acc[8];
  #pragma unroll
  for (int n = 0; n < 8; ++n) acc[n] = f32x4{0.f,0.f,0.f,0.f};

  for (int half = 0; half < 2; ++half){
    if (CSR){
      for (int task = t; task < 512; task += 256){
        int r = task >> 3, c = task & 7;
        int nd = n0 + r;
        bool ok = nd < N_NODES;
        float4 lo = {0,0,0,0}, hi = {0,0,0,0};
        if (ok){
          const float* src = (half == 0) ? (x_cur + (long)nd*DD + c*8)
                                         : (u_cur + (long)sBat[r]*DD + c*8);
          lo = *(const float4*)src; hi = *(const float4*)(src + 4);
        }
        uint4v v; v.x = pk2(lo.x, lo.y); v.y = pk2(lo.z, lo.w);
        v.z = pk2(hi.x, hi.y); v.w = pk2(hi.z, hi.w);
        st_chunk(sA, r, (half == 0) ? c : (8 + c), v);
      }
      if ((half == 0 && q < 2) || (half == 1 && q >= 2)){
        int cbase = (half == 0) ? (8 + q*4) : ((q - 2)*4);
        #pragma unroll
        for (int cc = 0; cc < 4; ++cc){
          uint4v v;
          v.x = pk2(s[cc*8+0], s[cc*8+1]); v.y = pk2(s[cc*8+2], s[cc*8+3]);
          v.z = pk2(s[cc*8+4], s[cc*8+5]); v.w = pk2(s[cc*8+6], s[cc*8+7]);
          st_chunk(sA, r4, cbase + cc, v);
        }
      }
    } else {
      for (int task = t; task < 1024; task += 256){
        int r = task >> 4, c = task & 15;
        int nd = n0 + r;
        bool ok = nd < N_NODES;
        float scale = 1.f;
        const float* src;
        if (half == 0){
          if (c < 8) src = x_cur + (long)nd*DD + c*8;
          else { src = agg_sum + (long)nd*HH + (c-8)*8; scale = sRinv[r]; }
        } else {
          if (c < 8){ src = agg_sum + (long)nd*HH + 64 + c*8; scale = sRinv[r]; }
          else src = u_cur + (long)sBat[r]*DD + (c-8)*8;
        }
        float4 lo = {0,0,0,0}, hi = {0,0,0,0};
        if (ok){ lo = *(const float4*)src; hi = *(const float4*)(src + 4); }
        uint4v v; v.x = pk2(lo.x*scale, lo.y*scale); v.y = pk2(lo.z*scale, lo.w*scale);
        v.z = pk2(hi.x*scale, hi.y*scale); v.w = pk2(hi.z*scale, hi.w*scale);
        st_chunk(sA, r, c, v);
      }
    }
    stage_b(sB, w_n21, 128, 256, half*128, t, 256);
    __syncthreads();
    gemm_acc<8>(sA, sB, wv, l15, lhi, acc);
    __syncthreads();
  }
  epi_lds<8, true>(sH, acc, b_n21, wv, l15, lhi);
  stage_b(sB, w_n22, 64, 128, 0, t, 256);
  __syncthreads();

  f32x4 acc2[4];
  #pragma unroll
  for (int n = 0; n < 4; ++n) acc2[n] = f32x4{0.f,0.f,0.f,0.f};
  gemm_acc<4>(sH, sB, wv, l15, lhi, acc2);

  #pragma unroll
  for (int n = 0; n < 4; ++n){
    float bv = b_n22[n*16 + l15];
    #pragma unroll
    for (int j = 0; j < 4; ++j){
      int r = wv*16 + lhi*4 + j;
      int nd = n0 + r;
      if (nd < N_NODES){
        int col = n*16 + l15;
        float v = acc2[n][j] + bv;
        long xg = (long)nd*DD + col;
        float vw = has_resid ? (v + x_resid[xg]) : v;
        x_out[xg] = vw;
        if (!has_resid) xbf_out[xg] = f2bf(vw);
        atomicAdd(&sNagg[sBat[r]*DD + col], v);
      }
    }
  }
  __syncthreads();
  for (int i = t; i < NG*DD; i += 256) atomicAdd(n_agg + i, sNagg[i]);
}

// ---------------- global (per-graph) MLP, fp32; e_agg from 32 replicas ----------------
__global__ void global_kernel(const float* __restrict__ u_cur, const float* __restrict__ n_agg,
                              const float* __restrict__ e_agg_rep, const float* __restrict__ cnt_b,
                              const float* __restrict__ cnt_e,
                              const float* __restrict__ g_w1, const float* __restrict__ g_b1,
                              const float* __restrict__ g_w2, const float* __restrict__ g_b2,
                              const float* __restrict__ u_resid, float* __restrict__ u_out,
                              int has_resid)
{
  int g = blockIdx.x, t = threadIdx.x;   // 192 threads
  __shared__ float uh[192];
  __shared__ float hb[128];
  float v;
  if (t < 64)       v = u_cur[g*64 + t];
  else if (t < 128) v = n_agg[g*64 + (t-64)] / fmaxf(cnt_b[g], 1.f);
  else {
    float s = 0.f;
    for (int c = 0; c < EREP; ++c) s += e_agg_rep[c*NG*DD + g*64 + (t-128)];
    v = s / fmaxf(cnt_e[g], 1.f);
  }
  uh[t] = v;
  __syncthreads();
  if (t < 128){
    float s = g_b1[t];
    for (int k = 0; k < 192; ++k) s += uh[k] * g_w1[k*128 + t];
    hb[t] = fmaxf(s, 0.f);
  }
  __syncthreads();
  if (t < 64){
    float s = g_b2[t];
    for (int k = 0; k < 128; ++k) s += hb[k] * g_w2[k*64 + t];
    if (has_resid) s += u_resid[g*64 + t];
    u_out[g*64 + t] = s;
  }
}

extern "C" void kernel_launch(void* const* d_in, const int* in_sizes, int n_in,
                              void* d_out, int out_size, void* d_ws, size_t ws_size,
                              hipStream_t stream)
{
  const float* x0   = (const float*)d_in[0];
  const float* e0   = (const float*)d_in[1];
  const float* u0   = (const float*)d_in[2];
  const float* e_w1 = (const float*)d_in[3];
  const float* e_b1 = (const float*)d_in[4];
  const float* e_w2 = (const float*)d_in[5];
  const float* e_b2 = (const float*)d_in[6];
  const float* e_w3 = (const float*)d_in[7];
  const float* e_b3 = (const float*)d_in[8];
  const float* n1_w1 = (const float*)d_in[9];
  const float* n1_b1 = (const float*)d_in[10];
  const float* n1_w2 = (const float*)d_in[11];
  const float* n1_b2 = (const float*)d_in[12];
  const float* n2_w1 = (const float*)d_in[13];
  const float* n2_b1 = (const float*)d_in[14];
  const float* n2_w2 = (const float*)d_in[15];
  const float* n2_b2 = (const float*)d_in[16];
  const float* g_w1 = (const float*)d_in[17];
  const float* g_b1 = (const float*)d_in[18];
  const float* g_w2 = (const float*)d_in[19];
  const float* g_b2 = (const float*)d_in[20];
  const int* edge_index = (const int*)d_in[21];
  const int* batch      = (const int*)d_in[22];

  float* out_x = (float*)d_out;
  float* out_e = out_x + (long)N_NODES*DD;
  float* out_u = out_e + (long)E_EDGES*DD;

  char* ws = (char*)d_ws;
  int*   deg    = (int*)(ws + 0);
  int*   off    = (int*)(ws + 200000);
  int*   cursor = (int*)(ws + 400000);
  int*   bsum   = (int*)(ws + 600000);
  int*   bbase  = (int*)(ws + 600256);
  float* cnt_eb = (float*)(ws + 600512);
  float* cnt_b  = (float*)(ws + 600576);
  float* n_agg  = (float*)(ws + 604736);
  float* biascf = (float*)(ws + 608832);          // 1024 B
  ushort* packed = (ushort*)(ws + 609856);        // 557056 -> ends 1,166,912
  float* e_agg_rep = (float*)(ws + 1166912);      // 131,072 -> ends 1,297,984
  ushort* xbf = (ushort*)(ws + 1297984);          // 6,400,000 -> ends 7,697,984
  const size_t big = 7697984;
  bool use_csr = ws_size >= (size_t)(big + 204800000 + 3200000);
  ushort* se_buf = (ushort*)(ws + big);
  int*    pos    = (int*)(ws + big + 204800000);
  float*  agg_sum = (float*)(ws + big);           // fallback overlay (25.6 MB)

  (void)hipMemsetAsync(deg, 0, 200000, stream);
  (void)hipMemsetAsync(cnt_eb, 0, 128, stream);
  pack_weights<<<896, 256, 0, stream>>>(e_w1, e_w2, e_w3, n1_w2, n2_w1, n2_w2, packed);
  make_wc<<<2, 256, 0, stream>>>(n1_w1, e_w3, n1_b1, e_b3, packed, biascf);
  hist_kernel<<<3125, 256, 0, stream>>>(edge_index, batch, deg, cnt_eb);
  count_nodes_kernel<<<196, 256, 0, stream>>>(batch, cnt_b);
  convert_x<<<1563, 256, 0, stream>>>(x0, xbf);
  if (use_csr){
    scan_a<<<NB_SCAN, 1024, 0, stream>>>(deg, bsum);
    scan_b<<<1, 64, 0, stream>>>(bsum, bbase);
    scan_c<<<NB_SCAN, 1024, 0, stream>>>(deg, bbase, off, cursor);
    fill_kernel<<<3125, 256, 0, stream>>>(edge_index, cursor, pos);
  }

  const float* xc = x0;
  const float* uc = u0;
  for (int l = 0; l < 2; ++l){
    (void)hipMemsetAsync(n_agg, 0, 4096, stream);
    (void)hipMemsetAsync(e_agg_rep, 0, EREP*NG*DD*4, stream);
    if (!use_csr){
      (void)hipMemsetAsync(agg_sum, 0, (size_t)N_NODES*HH*4, stream);
      if (l == 1) convert_x<<<1563, 256, 0, stream>>>(xc, xbf);
    }
    const ushort* P = packed + (long)l*139264;
    const float* ef32 = (l == 0) ? e0 : out_e;
    if (use_csr){
      if (l == 0)
        edge_fused<true, false><<<12500, 256, 0, stream>>>(
            xbf, e0, (const ushort*)out_e, uc, edge_index, batch, pos,
            P + 0, P + 32768, P + 49152, P + 114688, P + 57344,
            e_b1, e_b2, e_b3, biascf, n1_b2,
            out_e, e0, se_buf, agg_sum, e_agg_rep, 0);
      else
        edge_fused<true, true><<<12500, 256, 0, stream>>>(
            xbf, ef32, (const ushort*)out_e, uc, edge_index, batch, pos,
            P + 0, P + 32768, P + 49152, P + 114688, P + 57344,
            e_b1 + 128, e_b2 + 128, e_b3 + 64, biascf + 128, n1_b2 + 128,
            out_e, e0, se_buf, agg_sum, e_agg_rep, 1);
      node_kernel<true><<<782, 256, 0, stream>>>(
          xc, uc, x0, batch, se_buf, deg, off, agg_sum,
          P + 73728, P + 106496, n2_b1 + l*128, n2_b2 + l*64,
          out_x, xbf, n_agg, l == 1);
    } else {
      edge_fused<false, false><<<12500, 256, 0, stream>>>(
          xbf, ef32, (const ushort*)out_e, uc, edge_index, batch, pos,
          P + 0, P + 32768, P + 49152, P + 114688, P + 57344,
          e_b1 + l*128, e_b2 + l*128, e_b3 + l*64, biascf + l*128, n1_b2 + l*128,
          out_e, e0, se_buf, agg_sum, e_agg_rep, l == 1);
      node_kernel<false><<<782, 256, 0, stream>>>(
          xc, uc, x0, batch, se_buf, deg, off, agg_sum,
          P + 73728, P + 106496, n2_b1 + l*128, n2_b2 + l*64,
          out_x, xbf, n_agg, l == 1);
    }
    global_kernel<<<NG, 192, 0, stream>>>(
        uc, n_agg, e_agg_rep, cnt_b, cnt_eb,
        g_w1 + l*192*128, g_b1 + l*128, g_w2 + l*128*64, g_b2 + l*64,
        u0, out_u, l == 1);
    xc = out_x; uc = out_u;
  }
}

// Round 17
// 1690.520 us; speedup vs baseline: 1.0627x; 1.0627x over previous
//
#include <hip/hip_runtime.h>

#define N_NODES 50000
#define E_EDGES 800000
#define NG 16
#define DD 64
#define HH 128
#define NB_SCAN 49
#define EREP 32

typedef __attribute__((ext_vector_type(8))) __bf16 bf16x8;
typedef __attribute__((ext_vector_type(4))) float f32x4;
typedef unsigned int uint;
typedef unsigned short ushort;
typedef __attribute__((ext_vector_type(4))) uint uint4v;

#define MFMA16(a,b,c) __builtin_amdgcn_mfma_f32_16x16x32_bf16((a),(b),(c),0,0,0)

__device__ __forceinline__ ushort f2bf(float f){
  uint u = __builtin_bit_cast(uint, f);
  u += 0x7fffu + ((u >> 16) & 1u);
  return (ushort)(u >> 16);
}
__device__ __forceinline__ uint pk2(float a, float b){
  return (uint)f2bf(a) | ((uint)f2bf(b) << 16);
}
__device__ __forceinline__ float bflo(uint u){ return __builtin_bit_cast(float, u << 16); }
__device__ __forceinline__ float bfhi(uint u){ return __builtin_bit_cast(float, u & 0xffff0000u); }

// LDS-visibility barrier (no vmcnt drain)
__device__ __forceinline__ void bar(){
  asm volatile("s_waitcnt lgkmcnt(0)" ::: "memory");
  __builtin_amdgcn_s_barrier();
}
#define VMWAIT(n) asm volatile("s_waitcnt vmcnt(" #n ")" ::: "memory")

// async global->LDS, 16B per lane
__device__ __forceinline__ void gload16(const void* g, void* l){
  __builtin_amdgcn_global_load_lds(
      (const __attribute__((address_space(1))) unsigned int*)g,
      (__attribute__((address_space(3))) unsigned int*)l, 16, 0, 0);
}

// ---- pitch-256B LDS helpers (swizzled 16B chunks) ----
__device__ __forceinline__ bf16x8 ldfrag(const char* base, int row, int byteoff){
  uint4v v = *(const uint4v*)(base + row*256 + (byteoff ^ ((row & 7) << 4)));
  return __builtin_bit_cast(bf16x8, v);
}
__device__ __forceinline__ uint4v ld_chunk(const char* base, int row, int c16){
  return *(const uint4v*)(base + row*256 + ((c16*16) ^ ((row & 7) << 4)));
}
__device__ __forceinline__ void st_h(char* base, int row, int col, float v){
  *(ushort*)(base + row*256 + ((col*2) ^ ((row & 7) << 4))) = f2bf(v);
}
__device__ __forceinline__ void st_chunk(char* base, int row, int c16, uint4v v){
  *(uint4v*)(base + row*256 + ((c16*16) ^ ((row & 7) << 4))) = v;
}
// ---- pitch-128B LDS helpers ----
__device__ __forceinline__ bf16x8 ldfrag128(const char* base, int row, int byteoff){
  uint4v v = *(const uint4v*)(base + row*128 + (byteoff ^ ((row & 7) << 4)));
  return __builtin_bit_cast(bf16x8, v);
}
__device__ __forceinline__ uint4v ld_chunk128(const char* base, int row, int c16){
  return *(const uint4v*)(base + row*128 + ((c16*16) ^ ((row & 7) << 4)));
}
__device__ __forceinline__ void st_chunk128(char* base, int row, int c16, uint4v v){
  *(uint4v*)(base + row*128 + ((c16*16) ^ ((row & 7) << 4))) = v;
}
__device__ __forceinline__ void st_h128(char* base, int row, int col, float v){
  *(ushort*)(base + row*128 + ((col*2) ^ ((row & 7) << 4))) = f2bf(v);
}
__device__ __forceinline__ void pack16_128(char* dst, int r, int c16, const float* src){
  float4 lo = *(const float4*)src;
  float4 hi = *(const float4*)(src + 4);
  uint4v v; v.x = pk2(lo.x, lo.y); v.y = pk2(lo.z, lo.w);
  v.z = pk2(hi.x, hi.y); v.w = pk2(hi.z, hi.w);
  st_chunk128(dst, r, c16, v);
}

// node-kernel helpers (4 waves) — R2-proven
__device__ __forceinline__ void stage_b(char* sB, const ushort* wt,
                                        int Nout, int Ktot, int koff, int t, int stride){
  for (int task = t; task < Nout*16; task += stride){
    int n = task >> 4, c = task & 15;
    uint4v v = *(const uint4v*)(wt + (long)n*Ktot + koff + c*8);
    st_chunk(sB, n, c, v);
  }
}
template<int NT>
__device__ __forceinline__ void gemm_acc(const char* A, const char* B,
                                         int wv, int l15, int lhi, f32x4* acc){
  #pragma unroll
  for (int kt = 0; kt < 4; ++kt){
    bf16x8 a = ldfrag(A, wv*16 + l15, kt*64 + lhi*16);
    #pragma unroll
    for (int n = 0; n < NT; ++n){
      bf16x8 bb = ldfrag(B, n*16 + l15, kt*64 + lhi*16);
      acc[n] = MFMA16(a, bb, acc[n]);
    }
  }
}
template<int NT, bool RELU>
__device__ __forceinline__ void epi_lds(char* dst, const f32x4* acc, const float* bias,
                                        int wv, int l15, int lhi){
  #pragma unroll
  for (int n = 0; n < NT; ++n){
    float bv = bias[n*16 + l15];
    #pragma unroll
    for (int j = 0; j < 4; ++j){
      int r = wv*16 + lhi*4 + j;
      float v = acc[n][j] + bv;
      if (RELU) v = fmaxf(v, 0.f);
      st_h(dst, r, n*16 + l15, v);
    }
  }
}

// ---------------- x fp32 -> bf16 ----------------
__global__ void convert_x(const float* __restrict__ x, ushort* __restrict__ xbf){
  int i = blockIdx.x*256 + threadIdx.x;
  if (i < (N_NODES*DD)/8){
    float4 lo = *(const float4*)(x + (long)i*8);
    float4 hi = *(const float4*)(x + (long)i*8 + 4);
    uint4v v; v.x = pk2(lo.x, lo.y); v.y = pk2(lo.z, lo.w);
    v.z = pk2(hi.x, hi.y); v.w = pk2(hi.z, hi.w);
    *(uint4v*)(xbf + (long)i*8) = v;
  }
}

// ---------------- weight pack: fp32 [L][K][N] -> bf16 transposed [N][K] ----------
__global__ void pack_weights(const float* __restrict__ e1, const float* __restrict__ e2,
                             const float* __restrict__ e3, const float* __restrict__ n12,
                             const float* __restrict__ n21, const float* __restrict__ n22,
                             ushort* __restrict__ out){
  int idx = blockIdx.x * 256 + threadIdx.x;   // 2*114688
  int l = idx / 114688, r = idx % 114688;
  const float* src; int K, N, off;
  if      (r <  32768){ src = e1;  K = 256; N = 128; off = 0; }
  else if (r <  49152){ src = e2;  K = 128; N = 128; off = 32768; }
  else if (r <  57344){ src = e3;  K = 128; N = 64;  off = 49152; }
  else if (r <  73728){ src = n12; K = 128; N = 128; off = 57344; }
  else if (r < 106496){ src = n21; K = 256; N = 128; off = 73728; }
  else                { src = n22; K = 128; N = 64;  off = 106496; }
  int q = r - off; int k = q / N; int n = q % N;
  out[(long)l*139264 + off + n*K + k] = f2bf(src[(long)l*K*N + q]);
}

// fused weight Wc[n][k], k<64: n1_w1[k][n]; k>=64: sum_m e_w3[k-64][m]*n1_w1[64+m][n]
__global__ void make_wc(const float* __restrict__ n1w1, const float* __restrict__ ew3,
                        const float* __restrict__ n1b1, const float* __restrict__ eb3,
                        ushort* __restrict__ packed, float* __restrict__ biasc){
  int l = blockIdx.x, t = threadIdx.x;
  const float* W1 = n1w1 + (long)l*128*128;
  const float* W3 = ew3 + (long)l*128*64;
  ushort* wc = packed + (long)l*139264 + 114688;
  for (int i = t; i < 8192; i += 256){
    int k = i >> 7, n = i & 127;
    wc[n*192 + k] = f2bf(W1[k*128 + n]);
  }
  for (int i = t; i < 16384; i += 256){
    int k2 = i >> 7, n = i & 127;
    float s = 0.f;
    for (int m = 0; m < 64; ++m) s += W3[k2*64 + m] * W1[(64 + m)*128 + n];
    wc[n*192 + 64 + k2] = f2bf(s);
  }
  if (t < 128){
    float s = n1b1[l*128 + t];
    for (int m = 0; m < 64; ++m) s += eb3[l*64 + m] * W1[(64 + m)*128 + t];
    biasc[l*128 + t] = s;
  }
}

// ---------------- counts / CSR ----------------
__global__ void hist_kernel(const int* __restrict__ edge_index, const int* __restrict__ batch,
                            int* __restrict__ deg, float* __restrict__ cnt_eb){
  __shared__ float h[NG];
  int t = threadIdx.x;
  if (t < NG) h[t] = 0.f;
  __syncthreads();
  int e = blockIdx.x * 256 + t;
  if (e < E_EDGES){
    atomicAdd(deg + edge_index[E_EDGES + e], 1);
    atomicAdd(&h[batch[edge_index[e]]], 1.f);
  }
  __syncthreads();
  if (t < NG) atomicAdd(cnt_eb + t, h[t]);
}
__global__ void count_nodes_kernel(const int* __restrict__ batch, float* __restrict__ cnt_b){
  __shared__ float h[NG];
  int t = threadIdx.x;
  if (t < NG) h[t] = 0.f;
  __syncthreads();
  int n = blockIdx.x * 256 + t;
  if (n < N_NODES) atomicAdd(&h[batch[n]], 1.f);
  __syncthreads();
  if (t < NG) atomicAdd(cnt_b + t, h[t]);
}
__global__ void scan_a(const int* __restrict__ deg, int* __restrict__ bsum){
  __shared__ int red[1024];
  int i = blockIdx.x*1024 + threadIdx.x;
  red[threadIdx.x] = (i < N_NODES) ? deg[i] : 0;
  __syncthreads();
  for (int s = 512; s > 0; s >>= 1){
    if ((int)threadIdx.x < s) red[threadIdx.x] += red[threadIdx.x + s];
    __syncthreads();
  }
  if (threadIdx.x == 0) bsum[blockIdx.x] = red[0];
}
__global__ void scan_b(const int* __restrict__ bsum, int* __restrict__ bbase){
  if (threadIdx.x == 0){
    int run = 0;
    for (int b = 0; b < NB_SCAN; ++b){ int v = bsum[b]; bbase[b] = run; run += v; }
  }
}
__global__ void scan_c(const int* __restrict__ deg, const int* __restrict__ bbase,
                       int* __restrict__ off, int* __restrict__ cursor){
  __shared__ int sc[1024];
  int i = blockIdx.x*1024 + threadIdx.x;
  int v = (i < N_NODES) ? deg[i] : 0;
  sc[threadIdx.x] = v;
  __syncthreads();
  for (int d = 1; d < 1024; d <<= 1){
    int add = ((int)threadIdx.x >= d) ? sc[threadIdx.x - d] : 0;
    __syncthreads();
    sc[threadIdx.x] += add;
    __syncthreads();
  }
  if (i < N_NODES){
    int ex = sc[threadIdx.x] - v + bbase[blockIdx.x];
    off[i] = ex; cursor[i] = ex;
  }
}
__global__ void fill_kernel(const int* __restrict__ edge_index, int* __restrict__ cursor,
                            int* __restrict__ pos){
  int e = blockIdx.x*256 + threadIdx.x;
  if (e < E_EDGES){
    int c = edge_index[E_EDGES + e];
    pos[e] = atomicAdd(&cursor[c], 1);
  }
}

// ============ K123: gather -> GEMM1 -> GEMM2 -> H2 ============
template<bool EBF>
__global__ __launch_bounds__(256, 3) void k123_kernel(
    const ushort* __restrict__ xbf, const float* e_cur,
    const float* __restrict__ u_cur,
    const int* __restrict__ ei, const int* __restrict__ batch,
    const ushort* __restrict__ w1t, const ushort* __restrict__ w2t,
    const float* __restrict__ be1, const float* __restrict__ be2,
    ushort* h2g)
{
  __shared__ __align__(16) char lds[49152];
  __shared__ int sRow[128], sCol[128], sEb[128];
  char* A  = lds;
  char* B  = lds + 16384;
  char* OV = lds + 16384;
  const int t = threadIdx.x;
  const int wv = t >> 6, l15 = t & 15, lhi = (t >> 4) & 3;
  const int ebase = blockIdx.x * 128;

  if (t < 128){
    int r = ei[ebase + t];
    sRow[t] = r; sCol[t] = ei[E_EDGES + ebase + t]; sEb[t] = batch[r];
  }
  __syncthreads();

  f32x4 acc[2][8];
  #pragma unroll
  for (int m = 0; m < 2; ++m)
    #pragma unroll
    for (int n = 0; n < 8; ++n) acc[m][n] = f32x4{0,0,0,0};

  for (int c = 0; c < 4; ++c){
    #pragma unroll
    for (int it = 0; it < 4; ++it){
      int task = t + it*256, r = task >> 3, c16 = task & 7;
      if (c == 0)
        st_chunk128(A, r, c16, *(const uint4v*)(xbf + (long)sRow[r]*DD + c16*8));
      else if (c == 1)
        st_chunk128(A, r, c16, *(const uint4v*)(xbf + (long)sCol[r]*DD + c16*8));
      else if (c == 2){
        if (EBF)
          st_chunk128(A, r, c16, *(const uint4v*)(h2g + (long)(ebase + r)*HH + c16*8));
        else
          pack16_128(A, r, c16, e_cur + (long)(ebase + r)*DD + c16*8);
      } else
        pack16_128(A, r, c16, u_cur + (long)sEb[r]*DD + c16*8);
    }
    #pragma unroll
    for (int it = 0; it < 4; ++it){
      int task = t + it*256, n = task >> 3, c16 = task & 7;
      st_chunk128(B, n, c16, *(const uint4v*)(w1t + (long)n*256 + c*64 + c16*8));
    }
    __syncthreads();
    #pragma unroll
    for (int kt = 0; kt < 2; ++kt){
      bf16x8 a0 = ldfrag128(A, wv*32 + l15,      kt*64 + lhi*16);
      bf16x8 a1 = ldfrag128(A, wv*32 + 16 + l15, kt*64 + lhi*16);
      #pragma unroll
      for (int n = 0; n < 8; ++n){
        bf16x8 bb = ldfrag128(B, n*16 + l15, kt*64 + lhi*16);
        acc[0][n] = MFMA16(a0, bb, acc[0][n]);
        acc[1][n] = MFMA16(a1, bb, acc[1][n]);
      }
    }
    __syncthreads();
  }
  #pragma unroll
  for (int m = 0; m < 2; ++m)
    #pragma unroll
    for (int n = 0; n < 8; ++n){
      int col = n*16 + l15;
      float bv = be1[col];
      #pragma unroll
      for (int j = 0; j < 4; ++j)
        st_h(OV, wv*32 + m*16 + lhi*4 + j, col, fmaxf(acc[m][n][j] + bv, 0.f));
    }
  __syncthreads();

  #pragma unroll
  for (int m = 0; m < 2; ++m)
    #pragma unroll
    for (int n = 0; n < 8; ++n) acc[m][n] = f32x4{0,0,0,0};
  for (int kc = 0; kc < 2; ++kc){
    #pragma unroll
    for (int it = 0; it < 4; ++it){
      int task = t + it*256, n = task >> 3, c16 = task & 7;
      st_chunk128(A, n, c16, *(const uint4v*)(w2t + (long)n*128 + kc*64 + c16*8));
    }
    __syncthreads();
    #pragma unroll
    for (int kt = 0; kt < 2; ++kt){
      bf16x8 a0 = ldfrag(OV, wv*32 + l15,      kc*128 + kt*64 + lhi*16);
      bf16x8 a1 = ldfrag(OV, wv*32 + 16 + l15, kc*128 + kt*64 + lhi*16);
      #pragma unroll
      for (int n = 0; n < 8; ++n){
        bf16x8 bb = ldfrag128(A, n*16 + l15, kt*64 + lhi*16);
        acc[0][n] = MFMA16(a0, bb, acc[0][n]);
        acc[1][n] = MFMA16(a1, bb, acc[1][n]);
      }
    }
    __syncthreads();
  }
  #pragma unroll
  for (int m = 0; m < 2; ++m)
    #pragma unroll
    for (int n = 0; n < 8; ++n){
      int col = n*16 + l15;
      float bv = be2[col];
      #pragma unroll
      for (int j = 0; j < 4; ++j)
        st_h(OV, wv*32 + m*16 + lhi*4 + j, col, fmaxf(acc[m][n][j] + bv, 0.f));
    }
  __syncthreads();
  #pragma unroll
  for (int it = 0; it < 8; ++it){
    int task = t + it*256, r = task >> 4, c16 = task & 15;
    *(uint4v*)(h2g + (long)(ebase + r)*HH + c16*8) = ld_chunk(OV, r, c16);
  }
}

// ============ K45 v14: 4-slot ring, deep prefetch (M2 waits on nothing) ============
template<bool CSR>
__global__ __launch_bounds__(256, 2) void k45_kernel(
    const ushort* __restrict__ xbf, const ushort* h2g,
    const int* __restrict__ ei, const int* __restrict__ batch,
    const int* __restrict__ pos_arr,
    const ushort* __restrict__ w3t, const ushort* __restrict__ wct,
    const ushort* __restrict__ w5t,
    const float* __restrict__ be3, const float* __restrict__ biasc,
    const float* __restrict__ bn12,
    float* e_outf, const float* __restrict__ e_resid,
    ushort* __restrict__ se_buf, float* __restrict__ agg_sum,
    float* __restrict__ e_agg_rep, int has_resid)
{
  __shared__ __align__(16) char lds[65536];
  __shared__ float sEagg[NG*DD];
  __shared__ int sRow[128];   // r | eb<<16
  __shared__ int sDst[128];   // pos (CSR) or col
  char* S0 = lds;
  char* S1 = lds + 16384;
  char* S2 = lds + 32768;
  char* S3 = lds + 49152;
  char* OV = lds;             // 32KB over S0,S1 (H3, later SE)
  const int t = threadIdx.x;
  const int wv = t >> 6, lane = t & 63, l15 = t & 15, lhi = (t >> 4) & 3;
  const int ebase = blockIdx.x * 128;

  auto GL = [&](const ushort* base, long stride, int koff, char* slot){
    #pragma unroll
    for (int it = 0; it < 4; ++it){
      int q = (wv*4 + it)*64 + lane;
      int r = q >> 3, cp = q & 7;
      gload16(base + (long)r*stride + koff + ((cp ^ (r & 7))*8),
              slot + (wv*4 + it)*1024);
    }
  };

  // ---- prologue: indices, async Wc0/H2a/Wc1, w3 frags ----
  if (t < 128){
    int r = ei[ebase + t];
    sDst[t] = CSR ? pos_arr[ebase + t] : ei[E_EDGES + ebase + t];
    sRow[t] = r | (batch[r] << 16);
  }
  GL(wct, 192, 0, S1);                       // Wc0
  GL(h2g + (long)ebase*HH, HH, 0, S2);       // H2a
  GL(wct, 192, 64, S3);                      // Wc1
  bf16x8 b3[4][4];
  #pragma unroll
  for (int n = 0; n < 4; ++n)
    #pragma unroll
    for (int kk = 0; kk < 4; ++kk)
      b3[n][kk] = *(const bf16x8*)(w3t + (long)(n*16 + l15)*128 + kk*32 + lhi*8);
  for (int i = t; i < NG*DD; i += 256) sEagg[i] = 0.f;
  __syncthreads();                            // drain: Wc0,H2a,Wc1 resident; sRow visible

  #pragma unroll
  for (int it = 0; it < 4; ++it){             // x gather (bf16) -> S0
    int task = t + it*256, r = task >> 3, c16 = task & 7;
    st_chunk128(S0, r, c16,
        *(const uint4v*)(xbf + (long)(sRow[r] & 0xffff)*DD + c16*8));
  }
  __syncthreads();                            // S0 visible

  f32x4 acc4[2][8], acc3[2][4];
  #pragma unroll
  for (int m = 0; m < 2; ++m){
    #pragma unroll
    for (int n = 0; n < 8; ++n) acc4[m][n] = f32x4{0,0,0,0};
    #pragma unroll
    for (int n = 0; n < 4; ++n) acc3[m][n] = f32x4{0,0,0,0};
  }
  auto MM = [&](const char* A, const char* B){
    #pragma unroll
    for (int kt = 0; kt < 2; ++kt){
      bf16x8 a0 = ldfrag128(A, wv*32 + l15,      kt*64 + lhi*16);
      bf16x8 a1 = ldfrag128(A, wv*32 + 16 + l15, kt*64 + lhi*16);
      #pragma unroll
      for (int n = 0; n < 8; ++n){
        bf16x8 bb = ldfrag128(B, n*16 + l15, kt*64 + lhi*16);
        acc4[0][n] = MFMA16(a0, bb, acc4[0][n]);
        acc4[1][n] = MFMA16(a1, bb, acc4[1][n]);
      }
    }
  };
  auto MM3 = [&](const char* A, const char* B, int kkbase){
    #pragma unroll
    for (int kt = 0; kt < 2; ++kt){
      bf16x8 a0 = ldfrag128(A, wv*32 + l15,      kt*64 + lhi*16);
      bf16x8 a1 = ldfrag128(A, wv*32 + 16 + l15, kt*64 + lhi*16);
      #pragma unroll
      for (int n = 0; n < 8; ++n){
        bf16x8 bb = ldfrag128(B, n*16 + l15, kt*64 + lhi*16);
        acc4[0][n] = MFMA16(a0, bb, acc4[0][n]);
        acc4[1][n] = MFMA16(a1, bb, acc4[1][n]);
      }
      #pragma unroll
      for (int n = 0; n < 4; ++n){
        acc3[0][n] = MFMA16(a0, b3[n][kkbase + kt], acc3[0][n]);
        acc3[1][n] = MFMA16(a1, b3[n][kkbase + kt], acc3[1][n]);
      }
    }
  };

  // M1: x(S0) ⊗ Wc0(S1)
  MM(S0, S1);
  bar();                                      // retire M1 reads of S0,S1
  GL(h2g + (long)ebase*HH, HH, 64, S0);       // H2b  (4)
  GL(wct, 192, 128, S1);                      // Wc2  (4) -> 8 outstanding
  // M2: H2a(S2) ⊗ Wc1(S3) + G3(kk0,1) — operands prologue-resident, NO vm wait
  MM3(S2, S3, 0);
  bar();                                      // retire M2 reads of S2,S3
  GL(w5t, 128, 0, S2);                        // w5_0 (4)
  GL(w5t, 128, 64, S3);                       // w5_1 (4) -> 16 outstanding
  VMWAIT(8);                                  // oldest 8 (H2b, Wc2) resident
  __builtin_amdgcn_s_barrier();
  // M3: H2b(S0) ⊗ Wc2(S1) + G3(kk2,3)
  MM3(S0, S1, 2);
  bar();                                      // retire M3 reads -> S0,S1 free for OV
  // H3 epilogue -> OV
  #pragma unroll
  for (int m = 0; m < 2; ++m)
    #pragma unroll
    for (int n = 0; n < 8; ++n){
      int col = n*16 + l15;
      float bv = biasc[col];
      #pragma unroll
      for (int j = 0; j < 4; ++j)
        st_h(OV, wv*32 + m*16 + lhi*4 + j, col, fmaxf(acc4[m][n][j] + bv, 0.f));
    }
  VMWAIT(0);                                  // w5_0, w5_1 resident
  bar();                                      // OV visible
  // M4: H3(k0-63) ⊗ w5_0(S2); M5: H3(k64-127) ⊗ w5_1(S3) — no barrier between
  f32x4 acc5[2][8];
  #pragma unroll
  for (int m = 0; m < 2; ++m)
    #pragma unroll
    for (int n = 0; n < 8; ++n) acc5[m][n] = f32x4{0,0,0,0};
  #pragma unroll
  for (int kt = 0; kt < 2; ++kt){
    bf16x8 a0 = ldfrag(OV, wv*32 + l15,      kt*64 + lhi*16);
    bf16x8 a1 = ldfrag(OV, wv*32 + 16 + l15, kt*64 + lhi*16);
    #pragma unroll
    for (int n = 0; n < 8; ++n){
      bf16x8 bb = ldfrag128(S2, n*16 + l15, kt*64 + lhi*16);
      acc5[0][n] = MFMA16(a0, bb, acc5[0][n]);
      acc5[1][n] = MFMA16(a1, bb, acc5[1][n]);
    }
  }
  #pragma unroll
  for (int kt = 0; kt < 2; ++kt){
    bf16x8 a0 = ldfrag(OV, wv*32 + l15,      128 + kt*64 + lhi*16);
    bf16x8 a1 = ldfrag(OV, wv*32 + 16 + l15, 128 + kt*64 + lhi*16);
    #pragma unroll
    for (int n = 0; n < 8; ++n){
      bf16x8 bb = ldfrag128(S3, n*16 + l15, kt*64 + lhi*16);
      acc5[0][n] = MFMA16(a0, bb, acc5[0][n]);
      acc5[1][n] = MFMA16(a1, bb, acc5[1][n]);
    }
  }
  bar();                                      // OV/S2/S3 reads done

  if (CSR){
    // SE epi -> OV; layer0: e bf16 rows -> S2, plus sEagg
    #pragma unroll
    for (int m = 0; m < 2; ++m)
      #pragma unroll
      for (int n = 0; n < 8; ++n){
        int col = n*16 + l15;
        float bv = bn12[col];
        #pragma unroll
        for (int j = 0; j < 4; ++j)
          st_h(OV, wv*32 + m*16 + lhi*4 + j, col, acc5[m][n][j] + bv);
      }
    if (!has_resid){
      #pragma unroll
      for (int m = 0; m < 2; ++m)
        #pragma unroll
        for (int n = 0; n < 4; ++n){
          int col = n*16 + l15;
          float bv = be3[col];
          #pragma unroll
          for (int j = 0; j < 4; ++j){
            int row = wv*32 + m*16 + lhi*4 + j;
            float v = acc3[m][n][j] + bv;
            st_h128(S2, row, col, v);
            atomicAdd(&sEagg[(sRow[row] >> 16)*DD + col], v);
          }
        }
    }
    bar();
    #pragma unroll
    for (int it = 0; it < 8; ++it){
      int task = t + it*256, r = task >> 4, c16 = task & 15;
      *(uint4v*)(se_buf + (long)sDst[r]*HH + c16*8) = ld_chunk(OV, r, c16);
    }
    if (!has_resid){
      ushort* ebf = (ushort*)e_outf;          // bf16 into cols 0-63 of h2g rows
      #pragma unroll
      for (int it = 0; it < 4; ++it){
        int task = t + it*256, r = task >> 3, c16 = task & 7;
        *(uint4v*)(ebf + (long)(ebase + r)*HH + c16*8) = ld_chunk128(S2, r, c16);
      }
    } else {
      #pragma unroll
      for (int m = 0; m < 2; ++m)
        #pragma unroll
        for (int n = 0; n < 4; ++n){
          int col = n*16 + l15;
          float bv = be3[col];
          #pragma unroll
          for (int j = 0; j < 4; ++j){
            int row = wv*32 + m*16 + lhi*4 + j;
            float v = acc3[m][n][j] + bv;
            long eg = (long)(ebase + row)*DD + col;
            e_outf[eg] = v + e_resid[eg];
            atomicAdd(&sEagg[(sRow[row] >> 16)*DD + col], v);
          }
        }
    }
  } else {
    #pragma unroll
    for (int m = 0; m < 2; ++m)
      #pragma unroll
      for (int n = 0; n < 8; ++n){
        int col = n*16 + l15;
        float bv = bn12[col];
        #pragma unroll
        for (int j = 0; j < 4; ++j){
          int row = wv*32 + m*16 + lhi*4 + j;
          atomicAdd(agg_sum + (long)sDst[row]*HH + col, acc5[m][n][j] + bv);
        }
      }
    #pragma unroll
    for (int m = 0; m < 2; ++m)
      #pragma unroll
      for (int n = 0; n < 4; ++n){
        int col = n*16 + l15;
        float bv = be3[col];
        #pragma unroll
        for (int j = 0; j < 4; ++j){
          int row = wv*32 + m*16 + lhi*4 + j;
          float v = acc3[m][n][j] + bv;
          long eg = (long)(ebase + row)*DD + col;
          e_outf[eg] = has_resid ? (v + e_resid[eg]) : v;
          atomicAdd(&sEagg[(sRow[row] >> 16)*DD + col], v);
        }
      }
  }
  __syncthreads();
  float* dst = e_agg_rep + (long)(blockIdx.x & (EREP - 1))*NG*DD;
  for (int i = t; i < NG*DD; i += 256) atomicAdd(dst + i, sEagg[i]);
}

// ---------------- node kernel: mean-gather + node-MLP2; layer0 also emits xbf ---------
template<bool CSR>
__global__ __launch_bounds__(256, 2) void node_kernel(
    const float* __restrict__ x_cur, const float* __restrict__ u_cur,
    const float* __restrict__ x_resid, const int* __restrict__ batch,
    const ushort* __restrict__ se_buf, const int* __restrict__ deg,
    const int* __restrict__ off, const float* __restrict__ agg_sum,
    const ushort* __restrict__ w_n21, const ushort* __restrict__ w_n22,
    const float* __restrict__ b_n21, const float* __restrict__ b_n22,
    float* __restrict__ x_out, ushort* __restrict__ xbf_out,
    float* __restrict__ n_agg, int has_resid)
{
  __shared__ __align__(16) char sA[16384];
  __shared__ __align__(16) char sB[32768];
  __shared__ __align__(16) char sH[16384];
  __shared__ int sBat[64], sDeg[64], sOff[64];
  __shared__ float sRinv[64];
  __shared__ float sNagg[NG*DD];

  const int t = threadIdx.x;
  const int wv = t >> 6, ln = t & 63, l15 = ln & 15, lhi = ln >> 4;
  const int n0 = blockIdx.x * 64;

  if (t < 64){
    int nd = n0 + t;
    int ok = nd < N_NODES;
    sBat[t] = ok ? batch[nd] : 0;
    int d = ok ? deg[nd] : 0;
    sDeg[t] = d;
    sOff[t] = ok ? off[nd] : 0;
    sRinv[t] = 1.f / fmaxf((float)d, 1.f);
  }
  for (int i = t; i < NG*DD; i += 256) sNagg[i] = 0.f;
  __syncthreads();

  float s[32];
  const int r4 = t >> 2, q = t & 3;
  if (CSR){
    #pragma unroll
    for (int k = 0; k < 32; ++k) s[k] = 0.f;
    int d = sDeg[r4], o = sOff[r4];
    for (int i = 0; i < d; ++i){
      const ushort* src = se_buf + (long)(o + i)*HH + q*32;
      #pragma unroll
      for (int c = 0; c < 4; ++c){
        uint4v v = *(const uint4v*)(src + c*8);
        #pragma unroll
        for (int jj = 0; jj < 4; ++jj){
          s[c*8 + jj*2]     += bflo(v[jj]);
          s[c*8 + jj*2 + 1] += bfhi(v[jj]);
        }
      }
    }
    float riv = sRinv[r4];
    #pragma unroll
    for (int k = 0; k < 32; ++k) s[k] *= riv;
  }

  f32x4 acc[8];
  #pragma unroll
  for (int n = 0; n < 8; ++n) acc[n] = f32x4{0.f,0.f,0.f,0.f};

  for (int half = 0; half < 2; ++half){
    if (CSR){
      for (int task = t; task < 512; task += 256){
        int r = task >> 3, c = task & 7;
        int nd = n0 + r;
        bool ok = nd < N_NODES;
        float4 lo = {0,0,0,0}, hi = {0,0,0,0};
        if (ok){
          const float* src = (half == 0) ? (x_cur + (long)nd*DD + c*8)
                                         : (u_cur + (long)sBat[r]*DD + c*8);
          lo = *(const float4*)src; hi = *(const float4*)(src + 4);
        }
        uint4v v; v.x = pk2(lo.x, lo.y); v.y = pk2(lo.z, lo.w);
        v.z = pk2(hi.x, hi.y); v.w = pk2(hi.z, hi.w);
        st_chunk(sA, r, (half == 0) ? c : (8 + c), v);
      }
      if ((half == 0 && q < 2) || (half == 1 && q >= 2)){
        int cbase = (half == 0) ? (8 + q*4) : ((q - 2)*4);
        #pragma unroll
        for (int cc = 0; cc < 4; ++cc){
          uint4v v;
          v.x = pk2(s[cc*8+0], s[cc*8+1]); v.y = pk2(s[cc*8+2], s[cc*8+3]);
          v.z = pk2(s[cc*8+4], s[cc*8+5]); v.w = pk2(s[cc*8+6], s[cc*8+7]);
          st_chunk(sA, r4, cbase + cc, v);
        }
      }
    } else {
      for (int task = t; task < 1024; task += 256){
        int r = task >> 4, c = task & 15;
        int nd = n0 + r;
        bool ok = nd < N_NODES;
        float scale = 1.f;
        const float* src;
        if (half == 0){
          if (c < 8) src = x_cur + (long)nd*DD + c*8;
          else { src = agg_sum + (long)nd*HH + (c-8)*8; scale = sRinv[r]; }
        } else {
          if (c < 8){ src = agg_sum + (long)nd*HH + 64 + c*8; scale = sRinv[r]; }
          else src = u_cur + (long)sBat[r]*DD + (c-8)*8;
        }
        float4 lo = {0,0,0,0}, hi = {0,0,0,0};
        if (ok){ lo = *(const float4*)src; hi = *(const float4*)(src + 4); }
        uint4v v; v.x = pk2(lo.x*scale, lo.y*scale); v.y = pk2(lo.z*scale, lo.w*scale);
        v.z = pk2(hi.x*scale, hi.y*scale); v.w = pk2(hi.z*scale, hi.w*scale);
        st_chunk(sA, r, c, v);
      }
    }
    stage_b(sB, w_n21, 128, 256, half*128, t, 256);
    __syncthreads();
    gemm_acc<8>(sA, sB, wv, l15, lhi, acc);
    __syncthreads();
  }
  epi_lds<8, true>(sH, acc, b_n21, wv, l15, lhi);
  stage_b(sB, w_n22, 64, 128, 0, t, 256);
  __syncthreads();

  f32x4 acc2[4];
  #pragma unroll
  for (int n = 0; n < 4; ++n) acc2[n] = f32x4{0.f,0.f,0.f,0.f};
  gemm_acc<4>(sH, sB, wv, l15, lhi, acc2);

  #pragma unroll
  for (int n = 0; n < 4; ++n){
    float bv = b_n22[n*16 + l15];
    #pragma unroll
    for (int j = 0; j < 4; ++j){
      int r = wv*16 + lhi*4 + j;
      int nd = n0 + r;
      if (nd < N_NODES){
        int col = n*16 + l15;
        float v = acc2[n][j] + bv;
        long xg = (long)nd*DD + col;
        float vw = has_resid ? (v + x_resid[xg]) : v;
        x_out[xg] = vw;
        if (!has_resid) xbf_out[xg] = f2bf(vw);
        atomicAdd(&sNagg[sBat[r]*DD + col], v);
      }
    }
  }
  __syncthreads();
  for (int i = t; i < NG*DD; i += 256) atomicAdd(n_agg + i, sNagg[i]);
}

// ---------------- global (per-graph) MLP, fp32; e_agg from 32 replicas ----------------
__global__ void global_kernel(const float* __restrict__ u_cur, const float* __restrict__ n_agg,
                              const float* __restrict__ e_agg_rep, const float* __restrict__ cnt_b,
                              const float* __restrict__ cnt_e,
                              const float* __restrict__ g_w1, const float* __restrict__ g_b1,
                              const float* __restrict__ g_w2, const float* __restrict__ g_b2,
                              const float* __restrict__ u_resid, float* __restrict__ u_out,
                              int has_resid)
{
  int g = blockIdx.x, t = threadIdx.x;   // 192 threads
  __shared__ float uh[192];
  __shared__ float hb[128];
  float v;
  if (t < 64)       v = u_cur[g*64 + t];
  else if (t < 128) v = n_agg[g*64 + (t-64)] / fmaxf(cnt_b[g], 1.f);
  else {
    float s = 0.f;
    for (int c = 0; c < EREP; ++c) s += e_agg_rep[c*NG*DD + g*64 + (t-128)];
    v = s / fmaxf(cnt_e[g], 1.f);
  }
  uh[t] = v;
  __syncthreads();
  if (t < 128){
    float s = g_b1[t];
    for (int k = 0; k < 192; ++k) s += uh[k] * g_w1[k*128 + t];
    hb[t] = fmaxf(s, 0.f);
  }
  __syncthreads();
  if (t < 64){
    float s = g_b2[t];
    for (int k = 0; k < 128; ++k) s += hb[k] * g_w2[k*64 + t];
    if (has_resid) s += u_resid[g*64 + t];
    u_out[g*64 + t] = s;
  }
}

extern "C" void kernel_launch(void* const* d_in, const int* in_sizes, int n_in,
                              void* d_out, int out_size, void* d_ws, size_t ws_size,
                              hipStream_t stream)
{
  const float* x0   = (const float*)d_in[0];
  const float* e0   = (const float*)d_in[1];
  const float* u0   = (const float*)d_in[2];
  const float* e_w1 = (const float*)d_in[3];
  const float* e_b1 = (const float*)d_in[4];
  const float* e_w2 = (const float*)d_in[5];
  const float* e_b2 = (const float*)d_in[6];
  const float* e_w3 = (const float*)d_in[7];
  const float* e_b3 = (const float*)d_in[8];
  const float* n1_w1 = (const float*)d_in[9];
  const float* n1_b1 = (const float*)d_in[10];
  const float* n1_w2 = (const float*)d_in[11];
  const float* n1_b2 = (const float*)d_in[12];
  const float* n2_w1 = (const float*)d_in[13];
  const float* n2_b1 = (const float*)d_in[14];
  const float* n2_w2 = (const float*)d_in[15];
  const float* n2_b2 = (const float*)d_in[16];
  const float* g_w1 = (const float*)d_in[17];
  const float* g_b1 = (const float*)d_in[18];
  const float* g_w2 = (const float*)d_in[19];
  const float* g_b2 = (const float*)d_in[20];
  const int* edge_index = (const int*)d_in[21];
  const int* batch      = (const int*)d_in[22];

  float* out_x = (float*)d_out;
  float* out_e = out_x + (long)N_NODES*DD;
  float* out_u = out_e + (long)E_EDGES*DD;

  char* ws = (char*)d_ws;
  int*   deg    = (int*)(ws + 0);
  int*   off    = (int*)(ws + 200000);
  int*   cursor = (int*)(ws + 400000);
  int*   bsum   = (int*)(ws + 600000);
  int*   bbase  = (int*)(ws + 600256);
  float* cnt_eb = (float*)(ws + 600512);
  float* cnt_b  = (float*)(ws + 600576);
  float* n_agg  = (float*)(ws + 604736);
  float* biascf = (float*)(ws + 608832);          // 1024 B
  ushort* packed = (ushort*)(ws + 609856);        // 557056 -> ends 1,166,912
  float* e_agg_rep = (float*)(ws + 1166912);      // 131,072 -> ends 1,297,984
  ushort* xbf = (ushort*)(ws + 1297984);          // 6,400,000 -> ends 7,697,984
  const size_t big = 7697984;
  bool use_csr = ws_size >= (size_t)(big + 204800000 + 3200000);
  ushort* se_buf = (ushort*)(ws + big);
  int*    pos    = (int*)(ws + big + 204800000);
  float*  agg_sum = (float*)(ws + big);           // fallback overlay (25.6 MB)

  (void)hipMemsetAsync(deg, 0, 200000, stream);
  (void)hipMemsetAsync(cnt_eb, 0, 128, stream);
  pack_weights<<<896, 256, 0, stream>>>(e_w1, e_w2, e_w3, n1_w2, n2_w1, n2_w2, packed);
  make_wc<<<2, 256, 0, stream>>>(n1_w1, e_w3, n1_b1, e_b3, packed, biascf);
  hist_kernel<<<3125, 256, 0, stream>>>(edge_index, batch, deg, cnt_eb);
  count_nodes_kernel<<<196, 256, 0, stream>>>(batch, cnt_b);
  convert_x<<<1563, 256, 0, stream>>>(x0, xbf);
  if (use_csr){
    scan_a<<<NB_SCAN, 1024, 0, stream>>>(deg, bsum);
    scan_b<<<1, 64, 0, stream>>>(bsum, bbase);
    scan_c<<<NB_SCAN, 1024, 0, stream>>>(deg, bbase, off, cursor);
    fill_kernel<<<3125, 256, 0, stream>>>(edge_index, cursor, pos);
  }

  const float* xc = x0;
  const float* ec = e0;
  const float* uc = u0;
  for (int l = 0; l < 2; ++l){
    (void)hipMemsetAsync(n_agg, 0, 4096, stream);
    (void)hipMemsetAsync(e_agg_rep, 0, EREP*NG*DD*4, stream);
    if (!use_csr){
      (void)hipMemsetAsync(agg_sum, 0, (size_t)N_NODES*HH*4, stream);
      if (l == 1) convert_x<<<1563, 256, 0, stream>>>(xc, xbf);
    }
    const ushort* P = packed + (long)l*139264;
    if (use_csr && l == 1)
      k123_kernel<true><<<6250, 256, 0, stream>>>(
          xbf, ec, uc, edge_index, batch,
          P + 0, P + 32768, e_b1 + l*128, e_b2 + l*128,
          (ushort*)out_e);
    else
      k123_kernel<false><<<6250, 256, 0, stream>>>(
          xbf, ec, uc, edge_index, batch,
          P + 0, P + 32768, e_b1 + l*128, e_b2 + l*128,
          (ushort*)out_e);
    if (use_csr){
      k45_kernel<true><<<6250, 256, 0, stream>>>(
          xbf, (const ushort*)out_e, edge_index, batch, pos,
          P + 49152, P + 114688, P + 57344,
          e_b3 + l*64, biascf + l*128, n1_b2 + l*128,
          out_e, e0, se_buf, agg_sum, e_agg_rep, l == 1);
      node_kernel<true><<<782, 256, 0, stream>>>(
          xc, uc, x0, batch, se_buf, deg, off, agg_sum,
          P + 73728, P + 106496, n2_b1 + l*128, n2_b2 + l*64,
          out_x, xbf, n_agg, l == 1);
    } else {
      k45_kernel<false><<<6250, 256, 0, stream>>>(
          xbf, (const ushort*)out_e, edge_index, batch, pos,
          P + 49152, P + 114688, P + 57344,
          e_b3 + l*64, biascf + l*128, n1_b2 + l*128,
          out_e, e0, se_buf, agg_sum, e_agg_rep, l == 1);
      node_kernel<false><<<782, 256, 0, stream>>>(
          xc, uc, x0, batch, se_buf, deg, off, agg_sum,
          P + 73728, P + 106496, n2_b1 + l*128, n2_b2 + l*64,
          out_x, xbf, n_agg, l == 1);
    }
    global_kernel<<<NG, 192, 0, stream>>>(
        uc, n_agg, e_agg_rep, cnt_b, cnt_eb,
        g_w1 + l*192*128, g_b1 + l*128, g_w2 + l*128*64, g_b2 + l*64,
        u0, out_u, l == 1);
    xc = out_x; ec = out_e; uc = out_u;
  }
}